// Round 11
// baseline (131.916 us; speedup 1.0000x reference)
//
#include <hip/hip_runtime.h>

// Chamfer distance K=1 NN, both directions: EXACT three-tier grid search.
// N=4, P1=P2=8192, D=3, fp32. Points ~ N(0,1)^3.
//
// Overhead model (calibrated R0-R10): total = our kernels + 40us harness
// workspace-poison fill (256 MiB, unavoidable, in the timed stream) +
// ~2-6us launch gaps. Optimize kernel time only.
//
// Tier-1 (grid_search, 64 LANES PER QUERY): scan the 3^3 cell box.
//   Lanes 0..62 = 9 rows x 7 lanes; lane j of a row group takes candidates
//   s0+j, s0+j+7, ... (serial depth ~2 centrally). E-loads are
//   same-address within a group -> HW broadcast. 6-step shfl_xor
//   lexicographic (tt,idx) reduce; lane 0 runs the resolution test.
//   Resolution: per box face, distance(query, face plane) if the face is
//   strictly inside the grid, else +inf (no cells beyond it).
//   mf = min(6) - 1e-5. Resolved iff mf > 0 and bt < mf^2 - 2e-4
//   (slack covers |tt - true d2| rounding ~1e-4; conservative = more
//   fallback, never wrong). Unresolved -> list1.
// Tier-2 (grid_mid, wave per list1 query): 5^3 box, 25 rows x 2 lanes
//   (sparse-region queries -> few candidates), radius-2 resolution test,
//   residue -> list2.
// Tier-3 (grid_fallback, wave per list2 query): brute-force all 8192
//   targets, 4 independent chains; trivially exact. Expected ~hundreds.
// All tiers: candidate key = bitwise reference formula (contract off):
//   dot = ((qx*tx)+(qy*ty))+(qz*tz);  tt = fmaf(-2, dot, sp+sq),
//   sp/sq = ((x*x)+(y*y))+(z*z);
// selection = lexicographic min (tt, orig_idx) == numpy argmin semantics.
// Re-scanning cells across tiers is idempotent under the lexicographic
// min; scatter order inside a cell is atomic-nondeterministic but scanned
// SETS and the lexicographic min are order-independent -> deterministic.
//
// Binning: wide count/scan/scatter; the two clouds of a batch pack into
// one u32 histogram (w=0 low 16 bits, w=1 high 16; totals <= 8192 so no
// cross-half carry) -> single scan serves both clouds. Scan is shfl-based
// (1 barrier), round-8's proven pattern.
//
// ws byte layout (1.76 MiB <= 2 MiB):
//   [0       .. 524287 ]  u32 cnt[4 batches][32768 cells] packed lo/hi
//   [524288  .. 524291 ]  u32 listcnt1   (memset covers cnt+lcnt1+lcnt2)
//   [524292  .. 524295 ]  u32 listcnt2
//   [528384  .. 1576959]  v4f P[65536]  sorted (x,y,z,idx_bits), 16B align
//   [1576960 .. 1708031]  u16 list1[65536]
//   [1708032 .. 1839103]  u16 list2[65536]

typedef float v4f __attribute__((ext_vector_type(4)));

#define NC 32
#define NCELLS (NC * NC * NC)
#define GL0 -4.8f
#define GH 0.3f
#define GINVH (1.0f / 0.3f)
#define INFF __builtin_inff()

#define OFF_CNT   0
#define OFF_LCNT1 524288
#define OFF_LCNT2 524292
#define OFF_P     528384
#define OFF_LIST1 1576960
#define OFF_LIST2 1708032

__device__ __forceinline__ int cell1d(float v) {
#pragma clang fp contract(off)
    // sub-then-mul: no fma contraction possible; identical sequence in
    // count/scatter/search (cell-assignment consistency is critical).
    int c = (int)floorf((v - GL0) * GINVH);
    return min(max(c, 0), NC - 1);
}

// lexicographic (tt, idx) update
#define LEXMIN(bt, bi, tt, oi) \
    if ((tt) < (bt) || ((tt) == (bt) && (oi) < (bi))) { (bt) = (tt); (bi) = (oi); }

__global__ __launch_bounds__(256) void grid_count(const float* __restrict__ x,
                                                  const float* __restrict__ y,
                                                  unsigned int* __restrict__ cnt) {
#pragma clang fp contract(off)
    int g = blockIdx.x * 256 + threadIdx.x;   // 0..65535
    int k = g >> 13;                          // cloud = batch*2 + w
    int i = g & 8191;
    int n = k >> 1, w = k & 1;
    const float* src = w ? y : x;
    const float* p = src + (size_t)(n * 8192 + i) * 3;
    int cx = cell1d(p[0]);
    int cy = cell1d(p[1]);
    int cz = cell1d(p[2]);
    atomicAdd(&cnt[n * NCELLS + (cz * NC + cy) * NC + cx], w ? 65536u : 1u);
}

__global__ __launch_bounds__(1024) void grid_scan(unsigned int* __restrict__ cnt,
                                                  unsigned int* __restrict__ wsum_unused) {
    // One block per BATCH: exclusive prefix sum over 32768 packed cells.
    // lo/hi halves scan simultaneously (no cross-half carry: totals<=8192).
    // shfl-based: per-thread 32-sum -> wave inclusive shfl scan -> wave
    // totals via LDS (1 barrier) -> write back.
    __shared__ unsigned int wsum[16];
    int n = blockIdx.x;
    int t = threadIdx.x;
    int lane = t & 63;
    int wv = t >> 6;                          // wave 0..15
    unsigned int base = (unsigned int)n * NCELLS + (unsigned int)t * 32;
    unsigned int c[32];
    unsigned int s = 0;
#pragma unroll
    for (int j = 0; j < 32; ++j) { c[j] = cnt[base + j]; s += c[j]; }
    unsigned int incl = s;
#pragma unroll
    for (int off = 1; off < 64; off <<= 1) {
        unsigned int v = (unsigned int)__shfl_up((int)incl, off, 64);
        if (lane >= off) incl += v;
    }
    if (lane == 63) wsum[wv] = incl;          // wave total
    __syncthreads();
    unsigned int wbase = 0;
    for (int ww = 0; ww < wv; ++ww) wbase += wsum[ww];
    unsigned int run = wbase + incl - s;      // thread-chunk exclusive base
#pragma unroll
    for (int j = 0; j < 32; ++j) { unsigned int tmp = c[j]; cnt[base + j] = run; run += tmp; }
}

__global__ __launch_bounds__(256) void grid_scatter(const float* __restrict__ x,
                                                    const float* __restrict__ y,
                                                    unsigned int* __restrict__ cur,
                                                    v4f* __restrict__ P) {
#pragma clang fp contract(off)
    int g = blockIdx.x * 256 + threadIdx.x;   // 0..65535
    int k = g >> 13;
    int i = g & 8191;
    int n = k >> 1, w = k & 1;
    const float* src = w ? y : x;
    const float* p = src + (size_t)(n * 8192 + i) * 3;
    float a = p[0], b = p[1], c = p[2];
    int cell = (cell1d(c) * NC + cell1d(b)) * NC + cell1d(a);
    unsigned int old = atomicAdd(&cur[n * NCELLS + cell], w ? 65536u : 1u);
    unsigned int pos = (old >> (w ? 16 : 0)) & 0xffffu;
    v4f v;
    v.x = a; v.y = b; v.z = c; v.w = __uint_as_float((unsigned int)i);
    P[k * 8192 + (int)pos] = v;
    // afterwards cur[n][c] = packed end pointers for both clouds of batch n
}

// Tier-1: 64 lanes per query; 3^3 box; rows 0..8 -> lane groups of 7.
__global__ __launch_bounds__(256) void grid_search(const unsigned int* __restrict__ E,
                                                   const v4f* __restrict__ P,
                                                   float* __restrict__ out,
                                                   unsigned short* __restrict__ list1,
                                                   unsigned int* __restrict__ listcnt1) {
#pragma clang fp contract(off)
    int lane = threadIdx.x & 63;
    int g = blockIdx.x * 4 + (threadIdx.x >> 6);   // sorted slot 0..65535
    int k = g >> 13;
    int n = k >> 1, w = k & 1;                // w==0: x->y, w==1: y->x
    int tw = w ^ 1;
    int tsh = tw * 16;

    v4f q = P[g];                             // same addr across wave
    float qx = q.x, qy = q.y, qz = q.z;
    float sp = ((qx * qx) + (qy * qy)) + (qz * qz);
    int cx = cell1d(qx), cy = cell1d(qy), cz = cell1d(qz);

    const unsigned int* tE = E + n * NCELLS;
    const v4f* tP = P + (n * 2 + tw) * 8192;

    int x0 = max(cx - 1, 0), x1 = min(cx + 1, NC - 1);

    float bt = INFF; int bi = 0x7fffffff;

    int row = lane / 7;                       // 0..8 active, lane 63 -> 9
    int rl  = lane - row * 7;                 // 0..6
    if (row < 9) {
        // rows clamped at grid edges duplicate -> idempotent under lexmin.
        int z  = min(max(cz - 1 + row / 3, 0), NC - 1);
        int yy = min(max(cy - 1 + (row - (row / 3) * 3), 0), NC - 1);
        int rb = (z * NC + yy) * NC;
        int c0 = rb + x0;
        unsigned int s0 = c0 ? ((tE[c0 - 1] >> tsh) & 0xffffu) : 0u;
        unsigned int s1 = (tE[rb + x1] >> tsh) & 0xffffu;
        for (unsigned int kk = s0 + (unsigned int)rl; kk < s1; kk += 7u) {
            v4f t0 = tP[kk];
            float sq0 = ((t0.x * t0.x) + (t0.y * t0.y)) + (t0.z * t0.z);
            float dt0 = ((qx * t0.x) + (qy * t0.y)) + (qz * t0.z);
            float tt0 = fmaf(-2.0f, dt0, sp + sq0);
            int oi0 = (int)__float_as_uint(t0.w);
            LEXMIN(bt, bi, tt0, oi0)
        }
    }
    // full-wave lexicographic reduce (idle lanes hold INF).
#pragma unroll
    for (int off = 1; off < 64; off <<= 1) {
        float ot = __shfl_xor(bt, off, 64);
        int   oo = __shfl_xor(bi, off, 64);
        LEXMIN(bt, bi, ot, oo)
    }

    if (lane == 0) {
        // resolution test: faces at/past the grid edge -> +inf.
        int y0 = max(cy - 1, 0), y1 = min(cy + 1, NC - 1);
        int z0 = max(cz - 1, 0), z1 = min(cz + 1, NC - 1);
        float mfx0 = (x0 > 0)      ? qx - (GL0 + (float)x0 * GH)       : INFF;
        float mfx1 = (x1 < NC - 1) ? (GL0 + (float)(x1 + 1) * GH) - qx : INFF;
        float mfy0 = (y0 > 0)      ? qy - (GL0 + (float)y0 * GH)       : INFF;
        float mfy1 = (y1 < NC - 1) ? (GL0 + (float)(y1 + 1) * GH) - qy : INFF;
        float mfz0 = (z0 > 0)      ? qz - (GL0 + (float)z0 * GH)       : INFF;
        float mfz1 = (z1 < NC - 1) ? (GL0 + (float)(z1 + 1) * GH) - qz : INFF;
        float mf = fminf(fminf(fminf(mfx0, mfx1), fminf(mfy0, mfy1)),
                         fminf(mfz0, mfz1)) - 1e-5f;
        if (mf > 0.0f && bt < mf * mf - 2e-4f) {
            int qi = (int)__float_as_uint(q.w);
            int o = n * 8192 + qi;
            out[w * 32768 + o]         = bt;
            out[65536 + w * 32768 + o] = (float)bi;
        } else {
            unsigned int li = atomicAdd(listcnt1, 1u);
            list1[li] = (unsigned short)g;
        }
    }
}

// Tier-2: wave per list1 query; 5^3 box; 25 rows x 2 lanes.
__global__ __launch_bounds__(256) void grid_mid(const unsigned int* __restrict__ E,
                                                const v4f* __restrict__ P,
                                                float* __restrict__ out,
                                                const unsigned short* __restrict__ list1,
                                                const unsigned int* __restrict__ listcnt1,
                                                unsigned short* __restrict__ list2,
                                                unsigned int* __restrict__ listcnt2) {
#pragma clang fp contract(off)
    unsigned int cntv = *listcnt1;
    int wid = blockIdx.x * 4 + (threadIdx.x >> 6);   // 0..2047
    int lane = threadIdx.x & 63;

    for (unsigned int li = (unsigned int)wid; li < cntv; li += 2048u) {
        int g = (int)list1[li];
        int k = g >> 13;
        int n = k >> 1, w = k & 1;
        int tw = w ^ 1;
        int tsh = tw * 16;
        v4f q = P[g];
        float qx = q.x, qy = q.y, qz = q.z;
        float sp = ((qx * qx) + (qy * qy)) + (qz * qz);
        int cx = cell1d(qx), cy = cell1d(qy), cz = cell1d(qz);
        const unsigned int* tE = E + n * NCELLS;
        const v4f* tP = P + (n * 2 + tw) * 8192;

        int x0 = max(cx - 2, 0), x1 = min(cx + 2, NC - 1);

        float bt = INFF; int bi = 0x7fffffff;
        int row = lane >> 1;                  // 0..31; active rows 0..24
        int half = lane & 1;
        if (row < 25) {
            int z  = min(max(cz - 2 + row / 5, 0), NC - 1);
            int yy = min(max(cy - 2 + (row - (row / 5) * 5), 0), NC - 1);
            int rb = (z * NC + yy) * NC;
            int c0 = rb + x0;
            unsigned int s0 = c0 ? ((tE[c0 - 1] >> tsh) & 0xffffu) : 0u;
            unsigned int s1 = (tE[rb + x1] >> tsh) & 0xffffu;
            for (unsigned int kk = s0 + (unsigned int)half; kk < s1; kk += 2u) {
                v4f t0 = tP[kk];
                float sq0 = ((t0.x * t0.x) + (t0.y * t0.y)) + (t0.z * t0.z);
                float dt0 = ((qx * t0.x) + (qy * t0.y)) + (qz * t0.z);
                float tt0 = fmaf(-2.0f, dt0, sp + sq0);
                int oi0 = (int)__float_as_uint(t0.w);
                LEXMIN(bt, bi, tt0, oi0)
            }
        }
#pragma unroll
        for (int off = 1; off < 64; off <<= 1) {
            float ot = __shfl_xor(bt, off, 64);
            int   oo = __shfl_xor(bi, off, 64);
            LEXMIN(bt, bi, ot, oo)
        }

        if (lane == 0) {
            int y0 = max(cy - 2, 0), y1 = min(cy + 2, NC - 1);
            int z0 = max(cz - 2, 0), z1 = min(cz + 2, NC - 1);
            float mfx0 = (x0 > 0)      ? qx - (GL0 + (float)x0 * GH)       : INFF;
            float mfx1 = (x1 < NC - 1) ? (GL0 + (float)(x1 + 1) * GH) - qx : INFF;
            float mfy0 = (y0 > 0)      ? qy - (GL0 + (float)y0 * GH)       : INFF;
            float mfy1 = (y1 < NC - 1) ? (GL0 + (float)(y1 + 1) * GH) - qy : INFF;
            float mfz0 = (z0 > 0)      ? qz - (GL0 + (float)z0 * GH)       : INFF;
            float mfz1 = (z1 < NC - 1) ? (GL0 + (float)(z1 + 1) * GH) - qz : INFF;
            float mf = fminf(fminf(fminf(mfx0, mfx1), fminf(mfy0, mfy1)),
                             fminf(mfz0, mfz1)) - 1e-5f;
            if (mf > 0.0f && bt < mf * mf - 2e-4f) {
                int qi = (int)__float_as_uint(q.w);
                int o = n * 8192 + qi;
                out[w * 32768 + o]         = bt;
                out[65536 + w * 32768 + o] = (float)bi;
            } else {
                unsigned int l2 = atomicAdd(listcnt2, 1u);
                list2[l2] = (unsigned short)g;
            }
        }
    }
}

// Tier-3: wave per list2 query; brute-force all 8192; 4 chains for MLP.
__global__ __launch_bounds__(256) void grid_fallback(const unsigned short* __restrict__ list2,
                                                     const unsigned int* __restrict__ listcnt2,
                                                     const v4f* __restrict__ P,
                                                     float* __restrict__ out) {
#pragma clang fp contract(off)
    unsigned int cntv = *listcnt2;
    int wid = blockIdx.x * 4 + (threadIdx.x >> 6);   // 0..2047
    int lane = threadIdx.x & 63;

    for (unsigned int li = (unsigned int)wid; li < cntv; li += 2048u) {
        int g = (int)list2[li];
        int k = g >> 13;
        int n = k >> 1, w = k & 1;
        int tk = n * 2 + (w ^ 1);
        v4f q = P[g];
        float qx = q.x, qy = q.y, qz = q.z;
        float sp = ((qx * qx) + (qy * qy)) + (qz * qz);
        const v4f* tP = P + tk * 8192;

        float bt0 = INFF, bt1 = INFF, bt2 = INFF, bt3 = INFF;
        int bi0 = 0x7fffffff, bi1 = 0x7fffffff, bi2 = 0x7fffffff, bi3 = 0x7fffffff;
        for (int it = 0; it < 32; ++it) {            // 4 loads/iter, 4 chains
            v4f t0 = tP[(it * 4 + 0) * 64 + lane];   // coalesced
            v4f t1 = tP[(it * 4 + 1) * 64 + lane];
            v4f t2 = tP[(it * 4 + 2) * 64 + lane];
            v4f t3 = tP[(it * 4 + 3) * 64 + lane];
            float sq0 = ((t0.x * t0.x) + (t0.y * t0.y)) + (t0.z * t0.z);
            float dt0 = ((qx * t0.x) + (qy * t0.y)) + (qz * t0.z);
            float tt0 = fmaf(-2.0f, dt0, sp + sq0);
            int oi0 = (int)__float_as_uint(t0.w);
            LEXMIN(bt0, bi0, tt0, oi0)
            float sq1 = ((t1.x * t1.x) + (t1.y * t1.y)) + (t1.z * t1.z);
            float dt1 = ((qx * t1.x) + (qy * t1.y)) + (qz * t1.z);
            float tt1 = fmaf(-2.0f, dt1, sp + sq1);
            int oi1 = (int)__float_as_uint(t1.w);
            LEXMIN(bt1, bi1, tt1, oi1)
            float sq2 = ((t2.x * t2.x) + (t2.y * t2.y)) + (t2.z * t2.z);
            float dt2 = ((qx * t2.x) + (qy * t2.y)) + (qz * t2.z);
            float tt2 = fmaf(-2.0f, dt2, sp + sq2);
            int oi2 = (int)__float_as_uint(t2.w);
            LEXMIN(bt2, bi2, tt2, oi2)
            float sq3 = ((t3.x * t3.x) + (t3.y * t3.y)) + (t3.z * t3.z);
            float dt3 = ((qx * t3.x) + (qy * t3.y)) + (qz * t3.z);
            float tt3 = fmaf(-2.0f, dt3, sp + sq3);
            int oi3 = (int)__float_as_uint(t3.w);
            LEXMIN(bt3, bi3, tt3, oi3)
        }
        float bt = bt0; int bi = bi0;
        LEXMIN(bt, bi, bt1, bi1)
        LEXMIN(bt, bi, bt2, bi2)
        LEXMIN(bt, bi, bt3, bi3)
#pragma unroll
        for (int off = 32; off > 0; off >>= 1) {
            float ot = __shfl_xor(bt, off, 64);
            int   oo = __shfl_xor(bi, off, 64);
            LEXMIN(bt, bi, ot, oo)
        }
        if (lane == 0) {
            int qi = (int)__float_as_uint(q.w);
            int o = n * 8192 + qi;
            out[w * 32768 + o]         = bt;
            out[65536 + w * 32768 + o] = (float)bi;
        }
    }
}

extern "C" void kernel_launch(void* const* d_in, const int* in_sizes, int n_in,
                              void* d_out, int out_size, void* d_ws, size_t ws_size,
                              hipStream_t stream) {
    const float* x = (const float*)d_in[0];
    const float* y = (const float*)d_in[1];
    char* wsb = (char*)d_ws;
    unsigned int*   cnt      = (unsigned int*)(wsb + OFF_CNT);
    unsigned int*   listcnt1 = (unsigned int*)(wsb + OFF_LCNT1);
    unsigned int*   listcnt2 = (unsigned int*)(wsb + OFF_LCNT2);
    v4f*            P        = (v4f*)(wsb + OFF_P);
    unsigned short* list1    = (unsigned short*)(wsb + OFF_LIST1);
    unsigned short* list2    = (unsigned short*)(wsb + OFF_LIST2);
    float* out = (float*)d_out;

    hipMemsetAsync(wsb, 0, OFF_LCNT2 + 4, stream);    // cnt + both listcnts
    grid_count<<<256, 256, 0, stream>>>(x, y, cnt);
    grid_scan<<<4, 1024, 0, stream>>>(cnt, nullptr);
    grid_scatter<<<256, 256, 0, stream>>>(x, y, cnt, P);
    grid_search<<<16384, 256, 0, stream>>>(cnt, P, out, list1, listcnt1);
    grid_mid<<<512, 256, 0, stream>>>(cnt, P, out, list1, listcnt1, list2, listcnt2);
    grid_fallback<<<512, 256, 0, stream>>>(list2, listcnt2, P, out);
}